// Round 10
// baseline (394.548 us; speedup 1.0000x reference)
//
#include <hip/hip_runtime.h>
#include <hip/hip_fp16.h>

// Regrid, plane-lockstep direct gather (5-way field-split) + sequential fp16 reduce.
// y[n, b] = sum_{k: rows[k]==b} w[k] * x[n, flip(cols[k])]
// x: (140, 721*1440) f32, rows/cols: (260640,) i32, w: f32, out: (140, 181*360) f32.
//
// Preproc: 64B-line bucket hist + row hist -> 2-block scan -> permute:
// perm[j_cf] = (cf, w_bits, j_row); j_cf cf-line-sorted, j_row row-sorted.
// Gather: grid (nnz/256, 5). Thread = one cf-sorted nnz x one 28-field group:
// 28 scalar loads (wave's sorted cfs -> coalescer merges lines, L1 absorbs
// 4x line reuse; blocks sweep planes in near-lockstep -> HBM sees sharded
// memcpy, FETCH ~ 584MB proven r8), 14 packed fp16 pairs (VGPR ~48 -> high
// occupancy, ~5x outstanding misses vs r9), writes 56B sub-row of g[j_row]
// (8B-aligned uint2s -> clean 32B write sectors). Reduce: g rows for b
// contiguous -> fully sequential reads, f32 accumulate, LDS transpose,
// coalesced out. No global atomics in hot phases; d_out fully overwritten.

#define NXS 1440
#define NYS 721
#define N_A_CONST (721 * 1440)
#define N_B_CONST (181 * 360)
#define NBUCK (N_A_CONST / 16)     // 64,890 64B-line buckets
#define NFIELD 140
#define NGRP 5                     // field groups
#define FPG 28                     // fields per group
#define PPG 14                     // packed pairs per group
#define GDW 72                     // g row stride in dwords (288B = 9 x 32B sectors)

__device__ __forceinline__ int flip_col(int c) {
    int iy = c / NXS;
    int ix = c - iy * NXS;
    return (NYS - 1 - iy) * NXS + ix;
}

// ---------- preprocessing ----------

__global__ void zero_ws_kernel(int* __restrict__ p, int n) {
    int i = blockIdx.x * blockDim.x + threadIdx.x;
    int stride = gridDim.x * blockDim.x;
    for (; i < n; i += stride) p[i] = 0;
}

__global__ void hist2_kernel(const int* __restrict__ rows, const int* __restrict__ cols,
                             int* __restrict__ bcount, int* __restrict__ rcount, int nnz) {
    int k = blockIdx.x * blockDim.x + threadIdx.x;
    if (k >= nnz) return;
    int cf = flip_col(cols[k]);
    atomicAdd(&bcount[cf >> 4], 1);
    atomicAdd(&rcount[rows[k]], 1);
}

// block 0: bcount->boff (NBUCK); block 1: rcount->roff (N_B). 1024 thr x 64 elems.
__global__ void scan2_kernel(const int* __restrict__ bcount, int* __restrict__ boff,
                             const int* __restrict__ rcount, int* __restrict__ roff) {
    const int* in; int* out; int n;
    if (blockIdx.x == 0) { in = bcount; out = boff; n = NBUCK; }
    else                 { in = rcount; out = roff; n = N_B_CONST; }

    int t = threadIdx.x;
    int base = t * 64;
    int s = 0;
    for (int i = 0; i < 64; ++i) {
        int idx = base + i;
        s += (idx < n) ? in[idx] : 0;
    }
    int lane = t & 63;
    int wv = t >> 6;
    int incl = s;
    #pragma unroll
    for (int off = 1; off < 64; off <<= 1) {
        int u = __shfl_up(incl, off, 64);
        if (lane >= off) incl += u;
    }
    __shared__ int wsum[16];
    if (lane == 63) wsum[wv] = incl;
    __syncthreads();
    if (t < 16) {
        int v = wsum[t];
        #pragma unroll
        for (int off = 1; off < 16; off <<= 1) {
            int u = __shfl_up(v, off, 16);
            if (t >= off) v += u;
        }
        wsum[t] = v;
    }
    __syncthreads();
    int waveoff = (wv == 0) ? 0 : wsum[wv - 1];
    int run = waveoff + incl - s;
    for (int i = 0; i < 64; ++i) {
        int idx = base + i;
        if (idx < n) { out[idx] = run; run += in[idx]; }
    }
    if (t == 1023) out[n] = run;
}

// perm[j_cf] = (cf, w_bits, j_row, 0)
__global__ void perm2_kernel(const int* __restrict__ rows, const int* __restrict__ cols,
                             const float* __restrict__ w,
                             const int* __restrict__ boff, int* __restrict__ bcur,
                             const int* __restrict__ roff, int* __restrict__ rcur,
                             int4* __restrict__ perm, int nnz) {
    int k = blockIdx.x * blockDim.x + threadIdx.x;
    if (k >= nnz) return;
    int cf = flip_col(cols[k]);
    int bu = cf >> 4;
    int j_cf = boff[bu] + atomicAdd(&bcur[bu], 1);
    int b = rows[k];
    int j_row = roff[b] + atomicAdd(&rcur[b], 1);
    perm[j_cf] = make_int4(cf, __float_as_int(w[k]), j_row, 0);
}

// ---------- hot phases ----------

// grid (ceil(nnz/256), NGRP). Thread: nnz j, field group q -> 28 loads,
// 14 packed fp16 pairs, 56B store at g[j_row*GDW + q*PPG].
__global__ __launch_bounds__(256)
void gather_kernel(const float* __restrict__ x, const int4* __restrict__ perm,
                   unsigned int* __restrict__ g, int nnz) {
    int j = blockIdx.x * 256 + (int)threadIdx.x;
    if (j >= nnz) return;
    int q = blockIdx.y;
    int4 p = perm[j];
    const float* xp = x + p.x + (size_t)(q * FPG) * N_A_CONST;
    float wj = __int_as_float(p.y);

    unsigned int v[PPG];
    #pragma unroll
    for (int pp = 0; pp < PPG; ++pp) {
        float f0 = xp[(size_t)(2 * pp) * N_A_CONST];
        float f1 = xp[(size_t)(2 * pp + 1) * N_A_CONST];
        unsigned int lo = __half_as_ushort(__float2half(wj * f0));
        unsigned int hi = __half_as_ushort(__float2half(wj * f1));
        v[pp] = lo | (hi << 16);
    }

    unsigned int* gp = g + (size_t)p.z * GDW + q * PPG;
    #pragma unroll
    for (int i = 0; i < PPG / 2; ++i)
        *(uint2*)(gp + 2 * i) = make_uint2(v[2 * i], v[2 * i + 1]);
}

__device__ __forceinline__ float h2f_lo(unsigned int d) {
    return __half2float(__ushort_as_half((unsigned short)(d & 0xffffu)));
}
__device__ __forceinline__ float h2f_hi(unsigned int d) {
    return __half2float(__ushort_as_half((unsigned short)(d >> 16)));
}

// Block = 64 rows; g rows for b contiguous -> fully sequential reads.
__global__ __launch_bounds__(256)
void reduce_kernel(const unsigned int* __restrict__ g, const int* __restrict__ roff,
                   float* __restrict__ out) {
    __shared__ float lds[64][141];
    int b0 = blockIdx.x * 64;
    int lane = threadIdx.x & 63;
    int wv = threadIdx.x >> 6;

    for (int i = 0; i < 16; ++i) {
        int bl = wv * 16 + i;
        int b = b0 + bl;
        if (b < N_B_CONST) {
            int p0 = roff[b], p1 = roff[b + 1];
            float a0 = 0.f, a1 = 0.f, a2 = 0.f, a3 = 0.f;
            for (int pos = p0; pos < p1; ++pos) {
                const unsigned int* gr = g + (size_t)pos * GDW;
                unsigned int d = gr[lane];
                a0 += h2f_lo(d); a1 += h2f_hi(d);
                if (lane < 6) {
                    unsigned int e = gr[64 + lane];
                    a2 += h2f_lo(e); a3 += h2f_hi(e);
                }
            }
            lds[bl][2 * lane]     = a0;
            lds[bl][2 * lane + 1] = a1;
            if (lane < 6) {
                lds[bl][128 + 2 * lane] = a2;
                lds[bl][129 + 2 * lane] = a3;
            }
        }
    }
    __syncthreads();

    int nb = N_B_CONST - b0; if (nb > 64) nb = 64;
    for (int idx = threadIdx.x; idx < NFIELD * 64; idx += 256) {
        int f = idx >> 6;
        int rr = idx & 63;
        if (rr < nb)
            out[(size_t)f * N_B_CONST + b0 + rr] = lds[rr][f];
    }
}

// ---------- fallback ----------

__global__ void zero_out_kernel(float* __restrict__ out, int n) {
    int i = blockIdx.x * blockDim.x + threadIdx.x;
    int stride = gridDim.x * blockDim.x;
    for (; i < n; i += stride) out[i] = 0.0f;
}

__global__ void scatter_fallback_kernel(const float* __restrict__ x, const int* __restrict__ rows,
                                        const int* __restrict__ cols, const float* __restrict__ w,
                                        float* __restrict__ out, int nnz) {
    int k = blockIdx.x * blockDim.x + threadIdx.x;
    if (k >= nnz) return;
    int n = blockIdx.y;
    int cf = flip_col(cols[k]);
    float v = w[k] * x[(size_t)n * N_A_CONST + cf];
    atomicAdd(out + (size_t)n * N_B_CONST + rows[k], v);
}

extern "C" void kernel_launch(void* const* d_in, const int* in_sizes, int n_in,
                              void* d_out, int out_size, void* d_ws, size_t ws_size,
                              hipStream_t stream) {
    const float* x    = (const float*)d_in[0];
    const int*   rows = (const int*)d_in[1];
    const int*   cols = (const int*)d_in[2];
    const float* w    = (const float*)d_in[3];
    float* out = (float*)d_out;

    int nnz    = in_sizes[1];
    int nfield = in_sizes[0] / N_A_CONST;   // 140

    // ws layout (int units). Count/cursor arrays first: zeroed by one kernel.
    size_t o = 0;
    size_t bcount_o = o; o += NBUCK;
    size_t bcur_o   = o; o += NBUCK;
    size_t rcount_o = o; o += N_B_CONST;
    size_t rcur_o   = o; o += N_B_CONST;
    size_t zero_span = o;
    size_t boff_o   = o; o += NBUCK + 1;
    size_t roff_o   = o; o += N_B_CONST + 1;
    o = (o + 31) & ~(size_t)31;                 // 128B-align perm
    size_t perm_o   = o; o += 4 * (size_t)nnz;  // int4
    o = (o + 31) & ~(size_t)31;                 // 128B-align g
    size_t g_o      = o;
    size_t need_bytes = (g_o + (size_t)nnz * GDW) * sizeof(int);

    if (ws_size < need_bytes || nfield != NFIELD) {
        zero_out_kernel<<<2048, 256, 0, stream>>>(out, out_size);
        dim3 grid((nnz + 255) / 256, nfield);
        scatter_fallback_kernel<<<grid, 256, 0, stream>>>(x, rows, cols, w, out, nnz);
        return;
    }

    int*  wsI    = (int*)d_ws;
    int*  bcount = wsI + bcount_o;
    int*  bcur   = wsI + bcur_o;
    int*  rcount = wsI + rcount_o;
    int*  rcur   = wsI + rcur_o;
    int*  boff   = wsI + boff_o;
    int*  roff   = wsI + roff_o;
    int4* perm   = (int4*)(wsI + perm_o);
    unsigned int* g = (unsigned int*)(wsI + g_o);

    zero_ws_kernel<<<512, 256, 0, stream>>>(wsI, (int)zero_span);

    int nblk = (nnz + 255) / 256;   // 1019
    hist2_kernel<<<nblk, 256, 0, stream>>>(rows, cols, bcount, rcount, nnz);
    scan2_kernel<<<2, 1024, 0, stream>>>(bcount, boff, rcount, roff);
    perm2_kernel<<<nblk, 256, 0, stream>>>(rows, cols, w, boff, bcur, roff, rcur, perm, nnz);

    dim3 ggrid(nblk, NGRP);
    gather_kernel<<<ggrid, 256, 0, stream>>>(x, perm, g, nnz);

    int rblk = (N_B_CONST + 63) / 64;   // 1019
    reduce_kernel<<<rblk, 256, 0, stream>>>(g, roff, out);
}